// Round 8
// baseline (185.654 us; speedup 1.0000x reference)
//
#include <hip/hip_runtime.h>

// Problem constants (match reference)
#define V_ 100000
#define D_ 256
#define M_ 4096
#define C_ 4096
#define L_ 32
#define ROWS_MEMS (M_ + 1)          // 4097 rows in mems_enc (mems + xs_emb)
#define NTASK (1 + M_ + 1 + C_)     // 8194 encode row-tasks

// Atomic-spread partial buffers (round-7 win: ~32 adds/address, not 1025).
#define NBUF 32
#define BSTRIDE 260                  // 256 dims + esum@256, padded
#define ATT_BLOCKS 128
// ws float layout: part[NBUF*BSTRIDE] | enc[4097][256]
//   enc rows 0..4095 = mems encodings, row 4096 = xs encoding.

__device__ __forceinline__ float wave_allreduce_sum(float v) {
    #pragma unroll
    for (int off = 32; off >= 1; off >>= 1) v += __shfl_xor(v, off, 64);
    return v;
}

__device__ __forceinline__ float lane_bcast_f(float v, int l) {
    return __uint_as_float((unsigned)__builtin_amdgcn_readlane((int)__float_as_uint(v), l));
}

// fp32 gather encode: one wave per row, lane owns dims [4*lane, 4*lane+4).
// 8-deep scalarized batching (round-2 proven config).
__device__ __forceinline__ float4 encode_row_f(const int* __restrict__ tok_ptr,
                                               const char* __restrict__ ltb,
                                               const float* __restrict__ freqs,
                                               const int lane, const unsigned voff) {
    int tok = 0; float w = 0.f;
    if (lane < L_) { tok = tok_ptr[lane]; w = freqs[tok]; }
    const float s2 = wave_allreduce_sum(w * w);
    const float wn = w / sqrtf(s2);      // freqs > 0 -> s2 > 0

    float4 acc = make_float4(0.f, 0.f, 0.f, 0.f);
    #pragma unroll
    for (int lb = 0; lb < L_; lb += 8) {
        float4 v[8];
        #pragma unroll
        for (int j = 0; j < 8; ++j) {
            const unsigned t = (unsigned)__builtin_amdgcn_readlane(tok, lb + j);
            v[j] = *reinterpret_cast<const float4*>(ltb + t * 1024u + voff);
        }
        #pragma unroll
        for (int j = 0; j < 8; ++j) {
            const float wl = lane_bcast_f(wn, lb + j);
            acc.x = fmaf(wl, v[j].x, acc.x);
            acc.y = fmaf(wl, v[j].y, acc.y);
            acc.z = fmaf(wl, v[j].z, acc.z);
            acc.w = fmaf(wl, v[j].w, acc.w);
        }
    }
    return acc;
}

// ---------------------------------------------------------------------------
// K1: PURE encode. One wave per row-task, 4 waves/block, no LDS, no barriers,
// no atomics, no branch between att/out beyond the destination pointer.
//   rt==0 (xs)      -> enc row 4096
//   rt 1..4096      -> enc rows 0..4095 (mems encodings, ws-materialized)
//   rt==4097 (ys)   -> out_ys row 0
//   rt 4098..8193   -> out_ys rows 1..4096 (cands)
// Rationale: round-7 showed the reduction machinery (atomics) cost ~10 us on
// top of the gather; this strips ALL non-gather work from the 8194-wave
// kernel. Materializing enc costs 4.2 MB of L2 writes (~1 us).
// ---------------------------------------------------------------------------
__global__ __launch_bounds__(256) void encode_all(
    const int* __restrict__ xs, const int* __restrict__ mems,
    const int* __restrict__ ys, const int* __restrict__ cands,
    const float* __restrict__ lt, const float* __restrict__ freqs,
    float* __restrict__ enc,       // ws [4097][256]
    float* __restrict__ out_ys)    // d_out second half: [4097, 256]
{
    const int wave = threadIdx.x >> 6;
    const int lane = threadIdx.x & 63;
    const int d0 = lane * 4;
    const unsigned voff = (unsigned)d0 * 4u;
    const int rt = blockIdx.x * 4 + wave;
    if (rt >= NTASK) return;

    const int* tok_ptr; float* dst;
    if (rt == 0) {                       // xs -> enc row 4096
        tok_ptr = xs; dst = enc + (size_t)M_ * D_;
    } else if (rt <= M_) {               // mems row rt-1 -> enc row rt-1
        tok_ptr = mems + (size_t)(rt - 1) * L_;
        dst = enc + (size_t)(rt - 1) * D_;
    } else if (rt == M_ + 1) {           // ys -> out_ys row 0
        tok_ptr = ys; dst = out_ys;
    } else {                             // cands -> out_ys rows 1..4096
        const int c = rt - (M_ + 2);
        tok_ptr = cands + (size_t)c * L_;
        dst = out_ys + (size_t)(c + 1) * D_;
    }

    const float4 acc = encode_row_f(tok_ptr, (const char*)lt, freqs, lane, voff);
    *reinterpret_cast<float4*>(dst + d0) = acc;
}

// ---------------------------------------------------------------------------
// K2: attention reduction over the materialized enc rows (8.4 MB, L2-hot).
// 128 blocks x 4 waves; wave handles rows strided by 512. Each wave first
// rebuilds the xs fragment + ||xs|| from enc row 4096 (L2 broadcast), then
// per row: dot, norm, e=exp(cos) (cos in [-1,1], no max-sub), accumulate
// e*row in REGISTERS; block-combine via LDS atomics; one global atomicAdd
// per thread into part[blockIdx & 31] (4 adds/address).
// ---------------------------------------------------------------------------
__global__ __launch_bounds__(256) void attend(
    const float* __restrict__ enc, float* __restrict__ part)
{
    __shared__ float s_lred[D_];
    __shared__ float s_ered;

    const int tid  = threadIdx.x;
    const int wave = tid >> 6;
    const int lane = tid & 63;
    const int d0 = lane * 4;

    s_lred[tid] = 0.f;
    if (tid == 0) s_ered = 0.f;

    const float4 xf = *reinterpret_cast<const float4*>(enc + (size_t)M_ * D_ + d0);
    const float an2 = wave_allreduce_sum(xf.x*xf.x + xf.y*xf.y + xf.z*xf.z + xf.w*xf.w);
    const float an = fmaxf(sqrtf(an2), 1e-8f);
    __syncthreads();                    // s_lred zeroed before accumulation

    float4 av = make_float4(0.f, 0.f, 0.f, 0.f);
    float ae = 0.f;
    for (int r = blockIdx.x * 4 + wave; r < ROWS_MEMS; r += ATT_BLOCKS * 4) {
        const float4 v = *reinterpret_cast<const float4*>(enc + (size_t)r * D_ + d0);
        const float d = wave_allreduce_sum(v.x*xf.x + v.y*xf.y + v.z*xf.z + v.w*xf.w);
        const float q = wave_allreduce_sum(v.x*v.x + v.y*v.y + v.z*v.z + v.w*v.w);
        const float bn = fmaxf(sqrtf(q), 1e-8f);
        const float e = expf(d / (an * bn));          // same value on all lanes
        av.x = fmaf(e, v.x, av.x);
        av.y = fmaf(e, v.y, av.y);
        av.z = fmaf(e, v.z, av.z);
        av.w = fmaf(e, v.w, av.w);
        if (lane == 0) ae += e;
    }

    atomicAdd(&s_lred[d0 + 0], av.x);   // LDS: 4-wave combine
    atomicAdd(&s_lred[d0 + 1], av.y);
    atomicAdd(&s_lred[d0 + 2], av.z);
    atomicAdd(&s_lred[d0 + 3], av.w);
    if (lane == 0) atomicAdd(&s_ered, ae);
    __syncthreads();

    float* pb = part + (size_t)(blockIdx.x & (NBUF - 1)) * BSTRIDE;
    atomicAdd(&pb[tid], s_lred[tid]);
    if (tid == 0) atomicAdd(&pb[256], s_ered);
}

// ---------------------------------------------------------------------------
// K3: sum the partial buffers, normalize by the softmax denominator, tile
// into the 4097 out_xs rows. part[] is L2-hot (33 KB).
// ---------------------------------------------------------------------------
__global__ __launch_bounds__(256) void finalize_tile(
    const float* __restrict__ part, float* __restrict__ out_xs)
{
    float v = 0.f, g = 0.f;
    #pragma unroll
    for (int b = 0; b < NBUF; ++b) {
        v += part[b * BSTRIDE + threadIdx.x];
        g += part[b * BSTRIDE + 256];          // same addr across threads: broadcast
    }
    const float val = v / g;
    for (int r = blockIdx.x; r < ROWS_MEMS; r += gridDim.x)
        out_xs[(size_t)r * D_ + threadIdx.x] = val;
}

extern "C" void kernel_launch(void* const* d_in, const int* in_sizes, int n_in,
                              void* d_out, int out_size, void* d_ws, size_t ws_size,
                              hipStream_t stream) {
    const int*   xs    = (const int*)d_in[0];
    const int*   mems  = (const int*)d_in[1];
    const int*   ys    = (const int*)d_in[2];
    const int*   cands = (const int*)d_in[3];
    const float* lt    = (const float*)d_in[4];
    const float* freqs = (const float*)d_in[5];

    float* out    = (float*)d_out;
    float* out_xs = out;                                   // [4097, 256]
    float* out_ys = out + (size_t)ROWS_MEMS * D_;          // [4097, 256]

    float* part = (float*)d_ws;                            // [NBUF][BSTRIDE]
    float* enc  = part + NBUF * BSTRIDE;                   // [4097][256]

    hipMemsetAsync(part, 0, NBUF * BSTRIDE * sizeof(float), stream);
    encode_all<<<(NTASK + 3) / 4, 256, 0, stream>>>(
        xs, mems, ys, cands, lt, freqs, enc, out_ys);
    attend<<<ATT_BLOCKS, 256, 0, stream>>>(enc, part);
    finalize_tile<<<1024, 256, 0, stream>>>(part, out_xs);
}

// Round 9
// 182.092 us; speedup vs baseline: 1.0196x; 1.0196x over previous
//
#include <hip/hip_runtime.h>

// Problem constants (match reference)
#define V_ 100000
#define D_ 256
#define M_ 4096
#define C_ 4096
#define L_ 32
#define ROWS_MEMS (M_ + 1)          // 4097 rows in mems_enc (mems + xs_emb)
#define NTASK (1 + M_ + 1 + C_)     // 8194 encode row-tasks

// Atomic-spread partial buffers: 262,400 global atomicAdds previously hit the
// SAME 256 dwords (~1025 serialized RMWs per address at one L2 slice). Spread
// over 32 buffers keyed by blockIdx&31 -> ~32 adds/address. (round-7: -10 us)
#define NBUF 32
#define BSTRIDE 260                  // 256 dims + esum@256, padded (1040 B, odd lines)
// ws float layout: part[NBUF*BSTRIDE] | g_xs[257] (xf[256], an2)

__device__ __forceinline__ float wave_allreduce_sum(float v) {
    #pragma unroll
    for (int off = 32; off >= 1; off >>= 1) v += __shfl_xor(v, off, 64);
    return v;
}

__device__ __forceinline__ float lane_bcast_f(float v, int l) {
    return __uint_as_float((unsigned)__builtin_amdgcn_readlane((int)__float_as_uint(v), l));
}

// fp32 gather encode: one wave per row, lane owns dims [4*lane, 4*lane+4).
// 8-deep scalarized batching (round-2 proven config: VGPR 40).
// Session evidence: this gather runs at ~5.3 TB/s logical service — the
// random-1KB-row roofline. fp16 (half bytes), 2-rows-per-dwordx4 (half
// instructions), and 16-deep batching all measured FLAT; do not revisit.
__device__ __forceinline__ float4 encode_row_f(const int* __restrict__ tok_ptr,
                                               const char* __restrict__ ltb,
                                               const float* __restrict__ freqs,
                                               const int lane, const unsigned voff) {
    int tok = 0; float w = 0.f;
    if (lane < L_) { tok = tok_ptr[lane]; w = freqs[tok]; }
    const float s2 = wave_allreduce_sum(w * w);
    const float wn = w / sqrtf(s2);      // freqs > 0 -> s2 > 0

    float4 acc = make_float4(0.f, 0.f, 0.f, 0.f);
    #pragma unroll
    for (int lb = 0; lb < L_; lb += 8) {
        float4 v[8];
        #pragma unroll
        for (int j = 0; j < 8; ++j) {
            const unsigned t = (unsigned)__builtin_amdgcn_readlane(tok, lb + j);
            v[j] = *reinterpret_cast<const float4*>(ltb + t * 1024u + voff);
        }
        #pragma unroll
        for (int j = 0; j < 8; ++j) {
            const float wl = lane_bcast_f(wn, lb + j);
            acc.x = fmaf(wl, v[j].x, acc.x);
            acc.y = fmaf(wl, v[j].y, acc.y);
            acc.z = fmaf(wl, v[j].z, acc.z);
            acc.w = fmaf(wl, v[j].w, acc.w);
        }
    }
    return acc;
}

// ---------------------------------------------------------------------------
// K0: zero the partial buffers (replaces hipMemsetAsync) + one-wave fp32 xs
// encode -> g_xs[0..255], ||xs||^2 -> g_xs[256]. Hoists the xs prologue out
// of the 1025 att blocks.
// ---------------------------------------------------------------------------
__global__ __launch_bounds__(256) void xs_pre(
    const int* __restrict__ xs, const float* __restrict__ lt,
    const float* __restrict__ freqs, float* __restrict__ part,
    float* __restrict__ g_xs)
{
    for (int i = threadIdx.x; i < NBUF * BSTRIDE; i += 256) part[i] = 0.f;

    if (threadIdx.x < 64) {
        const int lane = threadIdx.x;
        const unsigned voff = (unsigned)lane * 16u;
        const float4 acc = encode_row_f(xs, (const char*)lt, freqs, lane, voff);
        *reinterpret_cast<float4*>(g_xs + lane * 4) = acc;
        const float an2 = wave_allreduce_sum(acc.x*acc.x + acc.y*acc.y +
                                             acc.z*acc.z + acc.w*acc.w);
        if (lane == 0) g_xs[256] = an2;
    }
}

// ---------------------------------------------------------------------------
// K1: fused encode + attention. One wave per row-task, 4 rows per block.
//   att rows: e = exp(cos(row, xs)) (cos in [-1,1], no max-sub needed);
//   accumulate e*row into LDS block-partial, then ONE global atomicAdd per
//   thread into partial buffer (blockIdx & 31).
//   ys/cands rows: encode -> straight to out_ys.
//   Round-8 A/B: splitting the reduction into a separate kernel over
//   ws-materialized encodings is NOT faster (185.7 vs 182.0) — the LDS/atomic
//   combine here is fully hidden under other blocks' gather latency.
// ---------------------------------------------------------------------------
__global__ __launch_bounds__(256) void encode_fused(
    const int* __restrict__ xs, const int* __restrict__ mems,
    const int* __restrict__ ys, const int* __restrict__ cands,
    const float* __restrict__ lt, const float* __restrict__ freqs,
    const float* __restrict__ g_xs,
    float* __restrict__ part,      // [NBUF][BSTRIDE]
    float* __restrict__ out_ys)    // d_out second half: [4097, 256]
{
    __shared__ float s_xf[D_];
    __shared__ float s_lred[D_];
    __shared__ float s_ered;
    __shared__ float s_an2;

    const int tid  = threadIdx.x;
    const int wave = tid >> 6;
    const int lane = tid & 63;
    const int d0 = lane * 4;
    const unsigned voff = (unsigned)d0 * 4u;
    const char* ltb = (const char*)lt;
    const int rt0 = blockIdx.x * 4;
    const bool block_has_att = (rt0 <= M_);   // blocks 0..1024 carry att rows

    s_lred[tid] = 0.f;
    if (tid == 0) s_ered = 0.f;
    if (block_has_att) {
        s_xf[tid] = g_xs[tid];               // precomputed fp32 xs encoding
        if (tid == 0) s_an2 = g_xs[256];
    }
    __syncthreads();

    const int rt = rt0 + wave;
    if (rt < NTASK) {
        const int* tok_ptr; float* dst = nullptr; bool has_att = false;
        if (rt == 0) {                       // xs row itself
            tok_ptr = xs; has_att = true;
        } else if (rt <= M_) {               // mems row rt-1
            tok_ptr = mems + (size_t)(rt - 1) * L_; has_att = true;
        } else if (rt == M_ + 1) {           // ys -> out_ys row 0
            tok_ptr = ys; dst = out_ys;
        } else {                             // cands -> out_ys rows 1..4096
            const int c = rt - (M_ + 2);
            tok_ptr = cands + (size_t)c * L_;
            dst = out_ys + (size_t)(c + 1) * D_;
        }

        const float4 acc = encode_row_f(tok_ptr, ltb, freqs, lane, voff);

        if (has_att) {
            const float4 xf = *reinterpret_cast<const float4*>(&s_xf[d0]);
            const float d = wave_allreduce_sum(acc.x*xf.x + acc.y*xf.y + acc.z*xf.z + acc.w*xf.w);
            const float q = wave_allreduce_sum(acc.x*acc.x + acc.y*acc.y + acc.z*acc.z + acc.w*acc.w);
            const float an = fmaxf(sqrtf(s_an2), 1e-8f);
            const float bn = fmaxf(sqrtf(q),  1e-8f);
            const float e = expf(d / (an * bn));     // same value on all lanes
            atomicAdd(&s_lred[d0 + 0], e * acc.x);   // LDS: 4-wave combine
            atomicAdd(&s_lred[d0 + 1], e * acc.y);
            atomicAdd(&s_lred[d0 + 2], e * acc.z);
            atomicAdd(&s_lred[d0 + 3], e * acc.w);
            if (lane == 0) atomicAdd(&s_ered, e);
        } else {
            *reinterpret_cast<float4*>(dst + d0) = acc;
        }
    }

    if (block_has_att) {
        __syncthreads();
        float* pb = part + (size_t)(blockIdx.x & (NBUF - 1)) * BSTRIDE;
        atomicAdd(&pb[tid], s_lred[tid]);            // ~32 adds/address
        if (tid == 0) atomicAdd(&pb[256], s_ered);
    }
}

// ---------------------------------------------------------------------------
// K2: sum the 32 partial buffers, normalize by the softmax denominator, and
// tile into the 4097 out_xs rows. part[] is L2-hot (33 KB).
// ---------------------------------------------------------------------------
__global__ __launch_bounds__(256) void finalize_tile(
    const float* __restrict__ part, float* __restrict__ out_xs)
{
    float v = 0.f, g = 0.f;
    #pragma unroll
    for (int b = 0; b < NBUF; ++b) {
        v += part[b * BSTRIDE + threadIdx.x];
        g += part[b * BSTRIDE + 256];          // same addr across threads: broadcast
    }
    const float val = v / g;
    for (int r = blockIdx.x; r < ROWS_MEMS; r += gridDim.x)
        out_xs[(size_t)r * D_ + threadIdx.x] = val;
}

extern "C" void kernel_launch(void* const* d_in, const int* in_sizes, int n_in,
                              void* d_out, int out_size, void* d_ws, size_t ws_size,
                              hipStream_t stream) {
    const int*   xs    = (const int*)d_in[0];
    const int*   mems  = (const int*)d_in[1];
    const int*   ys    = (const int*)d_in[2];
    const int*   cands = (const int*)d_in[3];
    const float* lt    = (const float*)d_in[4];
    const float* freqs = (const float*)d_in[5];

    float* out    = (float*)d_out;
    float* out_xs = out;                                   // [4097, 256]
    float* out_ys = out + (size_t)ROWS_MEMS * D_;          // [4097, 256]

    float* part = (float*)d_ws;                            // [NBUF][BSTRIDE]
    float* g_xs = part + NBUF * BSTRIDE;                   // [257]

    xs_pre<<<1, 256, 0, stream>>>(xs, lt, freqs, part, g_xs);
    encode_fused<<<(NTASK + 3) / 4, 256, 0, stream>>>(
        xs, mems, ys, cands, lt, freqs, g_xs, part, out_ys);
    finalize_tile<<<1024, 256, 0, stream>>>(part, out_xs);
}